// Round 6
// baseline (33.003 us; speedup 1.0000x reference)
//
#include <hip/hip_runtime.h>
#include <math.h>

// Morph2d: weighted 3x3 window min/max lerp.
// s = x_pad + 10*bias[c] (pad cell -> biasv, since raw pad = 0); tap = s * k[c,i,j]
// out = vmin + (vmax - vmin) * sigmoid(10*percentile[c]) - 10*bias[c]
//
// R6 = R4 structure (8x4 tile, all 6 input rows preloaded -> 24 independent
// loads in flight) + R5's bias-fold-at-load (no bk[], lower VGPR) + PLAIN
// stores (no nontemporal: in the timed replay loop input+output = 103 MB fit
// the 256 MB L3, so allocating stores keep output dirty-resident and avoid
// forcing 51 MB of HBM writes per replay).

#define B_ 16
#define C_ 64
#define H_ 112
#define W_ 112
#define TW 8
#define TH 4
#define GX (W_ / TW)   // 14
#define GY (H_ / TH)   // 28

typedef float f32x4 __attribute__((ext_vector_type(4)));

__global__ __launch_bounds__(256, 6) void morph2d_kernel(
    const float* __restrict__ x,
    const float* __restrict__ kern,   // (1,C,3,3)
    const float* __restrict__ bias,   // (C,)
    const float* __restrict__ perc,   // (C,)
    float* __restrict__ out)
{
    const int total = B_ * C_ * GY * GX;  // 401,408
    int t = blockIdx.x * blockDim.x + threadIdx.x;
    if (t >= total) return;

    int gx = t % GX;
    int r1 = t / GX;
    int ys = r1 % GY;
    int bc = r1 / GY;       // b*C + c
    int c  = bc % C_;

    float biasv = bias[c] * 10.0f;
    float p = 1.0f / (1.0f + expf(-perc[c] * 10.0f));

    const float* plane  = x   + (size_t)bc * (H_ * W_);
    float*       oplane = out + (size_t)bc * (H_ * W_);
    const int x0 = gx * TW;
    const int y0 = ys * TH;

    // Preload all TH+2 = 6 rows, cols x0-1 .. x0+8, biasv pre-added
    // (pad cell == biasv). All loads independent -> max MLP, one vmcnt wait.
    float s[TH + 2][TW + 2];
    #pragma unroll
    for (int i = 0; i < TH + 2; ++i) {
        int yy = y0 + i - 1;
        if ((unsigned)yy < (unsigned)H_) {
            const float* rp = plane + yy * W_ + x0;
            f32x4 a  = *reinterpret_cast<const f32x4*>(rp);
            f32x4 b4 = *reinterpret_cast<const f32x4*>(rp + 4);
            s[i][1] = a.x  + biasv;  s[i][2] = a.y  + biasv;
            s[i][3] = a.z  + biasv;  s[i][4] = a.w  + biasv;
            s[i][5] = b4.x + biasv;  s[i][6] = b4.y + biasv;
            s[i][7] = b4.z + biasv;  s[i][8] = b4.w + biasv;
            s[i][0] = (x0 > 0)       ? rp[-1] + biasv : biasv;
            s[i][9] = (x0 + TW < W_) ? rp[TW] + biasv : biasv;
        } else {
            #pragma unroll
            for (int j = 0; j < TW + 2; ++j) s[i][j] = biasv;
        }
    }

    float k[9];
    #pragma unroll
    for (int i = 0; i < 9; ++i) k[i] = kern[c * 9 + i];

    #pragma unroll
    for (int r = 0; r < TH; ++r) {
        float o[TW];
        #pragma unroll
        for (int q = 0; q < TW; ++q) {
            float t0 = s[r][q]     * k[0];
            float t1 = s[r][q + 1] * k[1];
            float t2 = s[r][q + 2] * k[2];
            float vmax = fmaxf(fmaxf(t0, t1), t2);
            float vmin = fminf(fminf(t0, t1), t2);
            t0 = s[r + 1][q]     * k[3];
            t1 = s[r + 1][q + 1] * k[4];
            t2 = s[r + 1][q + 2] * k[5];
            vmax = fmaxf(vmax, fmaxf(fmaxf(t0, t1), t2));
            vmin = fminf(vmin, fminf(fminf(t0, t1), t2));
            t0 = s[r + 2][q]     * k[6];
            t1 = s[r + 2][q + 1] * k[7];
            t2 = s[r + 2][q + 2] * k[8];
            vmax = fmaxf(vmax, fmaxf(fmaxf(t0, t1), t2));
            vmin = fminf(vmin, fminf(fminf(t0, t1), t2));
            o[q] = fmaf(vmax - vmin, p, vmin) - biasv;
        }

        float* orow = oplane + (y0 + r) * W_ + x0;
        *reinterpret_cast<f32x4*>(orow)     = f32x4{ o[0], o[1], o[2], o[3] };
        *reinterpret_cast<f32x4*>(orow + 4) = f32x4{ o[4], o[5], o[6], o[7] };
    }
}

extern "C" void kernel_launch(void* const* d_in, const int* in_sizes, int n_in,
                              void* d_out, int out_size, void* d_ws, size_t ws_size,
                              hipStream_t stream) {
    const float* x    = (const float*)d_in[0];
    const float* kern = (const float*)d_in[1];
    const float* bias = (const float*)d_in[2];
    const float* perc = (const float*)d_in[3];
    float* out = (float*)d_out;

    const int total = B_ * C_ * GY * GX;              // 401,408
    const int block = 256;
    const int grid  = (total + block - 1) / block;    // 1568
    morph2d_kernel<<<grid, block, 0, stream>>>(x, kern, bias, perc, out);
}

// Round 7
// 32.166 us; speedup vs baseline: 1.0260x; 1.0260x over previous
//
#include <hip/hip_runtime.h>
#include <math.h>

// Morph2d: weighted 3x3 window min/max lerp.
// tap(i,j) = (x_pad + 10*bias[c]) * k[c,i,j] = raw*k + bk  (bk = 10*bias*k, pad raw = 0)
// out = vmin + (vmax - vmin) * sigmoid(10*percentile[c]) - 10*bias[c]
//
// R7: kill the per-lane scalar halo loads (they were 32 cache-lines per
// instruction = 55% of all line traffic). Lane map: gx = lane%14 (14 x-tiles
// of TW=8 cover the full 112-px row), strip = wave*4 + lane/14 (4 row-strips
// per wave, lanes 56-63 idle). Halo pixels come from neighbor lanes via
// __shfl_up/__shfl_down; row loads are uniform (clamped y + select) so
// shuffles see no divergence. 12 vec loads + 8 NT stores per lane.

#define B_ 16
#define C_ 64
#define H_ 112
#define W_ 112
#define TW 8
#define TH 4
#define GX (W_ / TW)          // 14
#define GY (H_ / TH)          // 28
#define STRIPS (B_ * C_ * GY) // 28672 (bc, ys) row-strips
#define WAVES (STRIPS / 4)    // 7168

typedef float f32x4 __attribute__((ext_vector_type(4)));

__global__ __launch_bounds__(256) void morph2d_kernel(
    const float* __restrict__ x,
    const float* __restrict__ kern,   // (1,C,3,3)
    const float* __restrict__ bias,   // (C,)
    const float* __restrict__ perc,   // (C,)
    float* __restrict__ out)
{
    const int tid  = blockIdx.x * blockDim.x + threadIdx.x;
    const int wave = tid >> 6;
    const int lane = tid & 63;
    const int sub  = lane / 14;   // 0..4 (4 => idle)
    const int gx   = lane % 14;
    if (sub >= 4) return;         // 8 idle lanes; shuffle sources stay in 0..55

    const int strip = wave * 4 + sub;     // < 28672 exactly
    const int ys = strip % GY;
    const int bc = strip / GY;            // b*C + c
    const int c  = bc & (C_ - 1);

    const float biasv = bias[c] * 10.0f;
    const float p = 1.0f / (1.0f + expf(-perc[c] * 10.0f));

    float k[9], bk[9];
    #pragma unroll
    for (int i = 0; i < 9; ++i) {
        k[i]  = kern[c * 9 + i];
        bk[i] = k[i] * biasv;
    }

    const float* plane  = x   + (size_t)bc * (H_ * W_);
    float*       oplane = out + (size_t)bc * (H_ * W_);
    const int x0 = gx * TW;
    const int y0 = ys * TH;

    // Uniform preload of TH+2 = 6 rows (y clamped; pad row/col -> raw 0 via
    // select). Halo cols 0 and 9 via cross-lane shuffle of post-select values:
    // same-strip neighbors have identical yy/inY whenever the value is used.
    float s[TH + 2][TW + 2];
    #pragma unroll
    for (int i = 0; i < TH + 2; ++i) {
        int yy  = y0 + i - 1;
        int yyc = yy < 0 ? 0 : (yy > H_ - 1 ? H_ - 1 : yy);
        const float* rp = plane + yyc * W_ + x0;
        f32x4 a  = *reinterpret_cast<const f32x4*>(rp);
        f32x4 b4 = *reinterpret_cast<const f32x4*>(rp + 4);
        const bool inY = ((unsigned)yy < (unsigned)H_);
        s[i][1] = inY ? a.x  : 0.0f;  s[i][2] = inY ? a.y  : 0.0f;
        s[i][3] = inY ? a.z  : 0.0f;  s[i][4] = inY ? a.w  : 0.0f;
        s[i][5] = inY ? b4.x : 0.0f;  s[i][6] = inY ? b4.y : 0.0f;
        s[i][7] = inY ? b4.z : 0.0f;  s[i][8] = inY ? b4.w : 0.0f;
        float left  = __shfl_up(s[i][8], 1);   // neighbor's x0+7 == our x0-1
        float right = __shfl_down(s[i][1], 1); // neighbor's x0   == our x0+8
        s[i][0] = (gx > 0)      ? left  : 0.0f;
        s[i][9] = (gx < GX - 1) ? right : 0.0f;
    }

    #pragma unroll
    for (int r = 0; r < TH; ++r) {
        float o[TW];
        #pragma unroll
        for (int q = 0; q < TW; ++q) {
            float t0 = fmaf(s[r][q],     k[0], bk[0]);
            float t1 = fmaf(s[r][q + 1], k[1], bk[1]);
            float t2 = fmaf(s[r][q + 2], k[2], bk[2]);
            float vmax = fmaxf(fmaxf(t0, t1), t2);
            float vmin = fminf(fminf(t0, t1), t2);
            t0 = fmaf(s[r + 1][q],     k[3], bk[3]);
            t1 = fmaf(s[r + 1][q + 1], k[4], bk[4]);
            t2 = fmaf(s[r + 1][q + 2], k[5], bk[5]);
            vmax = fmaxf(vmax, fmaxf(fmaxf(t0, t1), t2));
            vmin = fminf(vmin, fminf(fminf(t0, t1), t2));
            t0 = fmaf(s[r + 2][q],     k[6], bk[6]);
            t1 = fmaf(s[r + 2][q + 1], k[7], bk[7]);
            t2 = fmaf(s[r + 2][q + 2], k[8], bk[8]);
            vmax = fmaxf(vmax, fmaxf(fmaxf(t0, t1), t2));
            vmin = fminf(vmin, fminf(fminf(t0, t1), t2));
            o[q] = fmaf(vmax - vmin, p, vmin) - biasv;
        }

        float* orow = oplane + (y0 + r) * W_ + x0;
        f32x4 lo = { o[0], o[1], o[2], o[3] };
        f32x4 hi = { o[4], o[5], o[6], o[7] };
        __builtin_nontemporal_store(lo, reinterpret_cast<f32x4*>(orow));
        __builtin_nontemporal_store(hi, reinterpret_cast<f32x4*>(orow + 4));
    }
}

extern "C" void kernel_launch(void* const* d_in, const int* in_sizes, int n_in,
                              void* d_out, int out_size, void* d_ws, size_t ws_size,
                              hipStream_t stream) {
    const float* x    = (const float*)d_in[0];
    const float* kern = (const float*)d_in[1];
    const float* bias = (const float*)d_in[2];
    const float* perc = (const float*)d_in[3];
    float* out = (float*)d_out;

    const int threads = WAVES * 64;                   // 458,752
    const int block = 256;
    const int grid  = threads / block;                // 1792
    morph2d_kernel<<<grid, block, 0, stream>>>(x, kern, bias, perc, out);
}

// Round 8
// 27.529 us; speedup vs baseline: 1.1988x; 1.1684x over previous
//
#include <hip/hip_runtime.h>
#include <math.h>

// Morph2d: weighted 3x3 window min/max lerp.
// LDS holds s = x_pad + 10*bias[c] (pad cell -> biasv); tap = s * k[c,i,j]
// out = vmin + (vmax - vmin) * sigmoid(10*percentile[c]) - 10*bias[c]
//
// R8: LDS-staged dense streaming. Block = one (b,c) plane quarter (28 rows).
//  - stage 30 rows x 112 (halo incl., bias folded) via FLAT CONTIGUOUS float4
//    loads (lane-consecutive addresses; interior quarter = one 13.4 KB span)
//  - compute 8-wide strips from LDS (aligned b32 + 2x f32x4 + b32 per row)
//  - dense contiguous plain f32x4 stores (consecutive lanes = consecutive cols)
// LDS 14.4 KB/block -> 8 blocks/CU = 32 waves/CU; grid 4096 = 2 rounds of 8.

#define B_ 16
#define C_ 64
#define H_ 112
#define W_ 112
#define QROWS 28             // output rows per block
#define SROWS (QROWS + 2)    // staged rows incl. top/bottom halo
#define LSTRIDE 120          // floats per LDS row; x=0 lives at idx 4 (16B align)
#define NF4 (W_ / 4)         // 28 float4 per image row

typedef float f32x4 __attribute__((ext_vector_type(4)));

__global__ __launch_bounds__(256) void morph2d_kernel(
    const float* __restrict__ x,
    const float* __restrict__ kern,   // (1,C,3,3)
    const float* __restrict__ bias,   // (C,)
    const float* __restrict__ perc,   // (C,)
    float* __restrict__ out)
{
    __shared__ float lds[SROWS * LSTRIDE];   // 14400 B

    const int tid   = threadIdx.x;
    const int blk   = blockIdx.x;       // plane*4 + quarter
    const int q     = blk & 3;
    const int plane = blk >> 2;         // b*C + c
    const int c     = plane & (C_ - 1);
    const int r0    = q * QROWS;        // first output row of this quarter

    const float biasv = bias[c] * 10.0f;
    const float p = 1.0f / (1.0f + expf(-perc[c] * 10.0f));

    const float* gplane = x   + (size_t)plane * (H_ * W_);
    float*       oplane = out + (size_t)plane * (H_ * W_);

    // ---- stage: rows r0-1 .. r0+28 (clamped -> biasv), bias folded ----
    for (int f = tid; f < SROWS * NF4; f += 256) {      // 840 float4
        int srow = f / NF4;
        int col4 = f - srow * NF4;
        int irow = r0 - 1 + srow;
        f32x4 v;
        if ((unsigned)irow < (unsigned)H_) {
            v = *reinterpret_cast<const f32x4*>(gplane + irow * W_ + col4 * 4);
            v.x += biasv; v.y += biasv; v.z += biasv; v.w += biasv;
        } else {
            v.x = biasv; v.y = biasv; v.z = biasv; v.w = biasv;
        }
        *reinterpret_cast<f32x4*>(&lds[srow * LSTRIDE + 4 + col4 * 4]) = v;
    }
    // x-pads: idx 3 (x=-1) and idx 116 (x=112) of every staged row
    if (tid < SROWS) {
        lds[tid * LSTRIDE + 3]   = biasv;
        lds[tid * LSTRIDE + 116] = biasv;
    }
    __syncthreads();

    float k[9];
    #pragma unroll
    for (int i = 0; i < 9; ++i) k[i] = kern[c * 9 + i];

    // ---- compute: 392 strips of 8 outputs, row-major (gx fastest) ----
    for (int s = tid; s < QROWS * 14; s += 256) {
        int row = s / 14;               // 0..27
        int gx  = s - row * 14;         // 0..13
        // window floats per staged row: idx 3+8gx .. 12+8gx  (x-1 .. x+8)
        float w[3][10];
        #pragma unroll
        for (int dr = 0; dr < 3; ++dr) {
            const float* l = &lds[(row + dr) * LSTRIDE + 3 + gx * 8];
            w[dr][0] = l[0];
            f32x4 a = *reinterpret_cast<const f32x4*>(l + 1);   // 16B aligned
            f32x4 b = *reinterpret_cast<const f32x4*>(l + 5);   // 16B aligned
            w[dr][1] = a.x; w[dr][2] = a.y; w[dr][3] = a.z; w[dr][4] = a.w;
            w[dr][5] = b.x; w[dr][6] = b.y; w[dr][7] = b.z; w[dr][8] = b.w;
            w[dr][9] = l[9];
        }

        float o[8];
        #pragma unroll
        for (int qq = 0; qq < 8; ++qq) {
            float t0 = w[0][qq]     * k[0];
            float t1 = w[0][qq + 1] * k[1];
            float t2 = w[0][qq + 2] * k[2];
            float vmax = fmaxf(fmaxf(t0, t1), t2);
            float vmin = fminf(fminf(t0, t1), t2);
            t0 = w[1][qq]     * k[3];
            t1 = w[1][qq + 1] * k[4];
            t2 = w[1][qq + 2] * k[5];
            vmax = fmaxf(vmax, fmaxf(fmaxf(t0, t1), t2));
            vmin = fminf(vmin, fminf(fminf(t0, t1), t2));
            t0 = w[2][qq]     * k[6];
            t1 = w[2][qq + 1] * k[7];
            t2 = w[2][qq + 2] * k[8];
            vmax = fmaxf(vmax, fmaxf(fmaxf(t0, t1), t2));
            vmin = fminf(vmin, fminf(fminf(t0, t1), t2));
            o[qq] = fmaf(vmax - vmin, p, vmin) - biasv;
        }

        float* orow = oplane + (r0 + row) * W_ + gx * 8;
        *reinterpret_cast<f32x4*>(orow)     = f32x4{ o[0], o[1], o[2], o[3] };
        *reinterpret_cast<f32x4*>(orow + 4) = f32x4{ o[4], o[5], o[6], o[7] };
    }
}

extern "C" void kernel_launch(void* const* d_in, const int* in_sizes, int n_in,
                              void* d_out, int out_size, void* d_ws, size_t ws_size,
                              hipStream_t stream) {
    const float* x    = (const float*)d_in[0];
    const float* kern = (const float*)d_in[1];
    const float* bias = (const float*)d_in[2];
    const float* perc = (const float*)d_in[3];
    float* out = (float*)d_out;

    const int grid = B_ * C_ * 4;   // 4096 blocks (one per plane quarter)
    morph2d_kernel<<<grid, 256, 0, stream>>>(x, kern, bias, perc, out);
}